// Round 10
// baseline (427.370 us; speedup 1.0000x reference)
//
#include <hip/hip_runtime.h>
#include <hip/hip_bf16.h>

#define D_MODEL 1024
#define N_HEADS 16
#define DK      64
#define SEQ     2048
#define BATCH   2
#define D_FF    4096
#define ROWS    (BATCH*SEQ)   // 4096
#define LN_EPS  1e-6f
#define SSTR    72            // fattn Qs/Ps row stride (bf16): 64 data + 8 pad
#define LOG2E   1.4426950408889634f

typedef __hip_bfloat16 bf16;
typedef __attribute__((ext_vector_type(8))) short frag8;   // 8 bf16 (MFMA A/B)
typedef __attribute__((ext_vector_type(4))) float facc4;   // 4 f32 (MFMA C/D)

__device__ inline float bf2f(unsigned short u){ return __uint_as_float(((unsigned)u) << 16); }
__device__ inline float toF(bf16 v){ return __bfloat162float(v); }
__device__ inline unsigned short f2bu(float f){ bf16 h = __float2bfloat16(f); return *reinterpret_cast<unsigned short*>(&h); }

__device__ inline float ld1(const void* p, size_t idx, bool f32) {
    return f32 ? ((const float*)p)[idx] : toF(((const bf16*)p)[idx]);
}
// 4 consecutive input-dtype elems -> float[4] (idx 4-aligned).
__device__ inline void ld4f(const void* p, size_t idx, bool f32, float* o) {
    if (f32) {
        const float4 f = *reinterpret_cast<const float4*>((const float*)p + idx);
        o[0] = f.x; o[1] = f.y; o[2] = f.z; o[3] = f.w;
    } else {
        const ushort4 u = *reinterpret_cast<const ushort4*>((const unsigned short*)p + idx);
        o[0] = bf2f(u.x); o[1] = bf2f(u.y); o[2] = bf2f(u.z); o[3] = bf2f(u.w);
    }
}

struct U8 { unsigned short v[8]; };
__device__ inline U8 ld8bf(const void* p, size_t idx, bool f32) {
    U8 r;
    if (!f32) {
        *reinterpret_cast<uint4*>(r.v) = *reinterpret_cast<const uint4*>((const unsigned short*)p + idx);
    } else {
        const float* f = (const float*)p + idx;
        const float4 a = *reinterpret_cast<const float4*>(f);
        const float4 b = *reinterpret_cast<const float4*>(f + 4);
        r.v[0]=f2bu(a.x); r.v[1]=f2bu(a.y); r.v[2]=f2bu(a.z); r.v[3]=f2bu(a.w);
        r.v[4]=f2bu(b.x); r.v[5]=f2bu(b.y); r.v[6]=f2bu(b.z); r.v[7]=f2bu(b.w);
    }
    return r;
}

// Async global->LDS, 16B/lane. LDS dst is wave-uniform base; lane i -> dst+i*16B.
__device__ inline void gld16(const void* g, void* l) {
    __builtin_amdgcn_global_load_lds(
        reinterpret_cast<const __attribute__((address_space(1))) void*>(
            reinterpret_cast<uintptr_t>(g)),
        reinterpret_cast<__attribute__((address_space(3))) void*>(
            (unsigned int)reinterpret_cast<uintptr_t>(l)),
        16, 0, 0);
}

// Dtype probe: fp32 bits misread as bf16 give Inf/NaN/huge values.
__global__ void probe_kernel(const void* __restrict__ xp, int* __restrict__ flag) {
    __shared__ int hit;
    if (threadIdx.x == 0) hit = 0;
    __syncthreads();
    const bf16* p = (const bf16*)xp;
    int bad = 0;
    for (int i = threadIdx.x; i < 8192; i += 256) {
        float v = fabsf(toF(p[i]));
        if (!(v <= 1e5f)) bad = 1;
    }
    if (bad) atomicOr(&hit, 1);
    __syncthreads();
    if (threadIdx.x == 0) *flag = hit;   // 1 => inputs are fp32
}

// x (flag dtype) -> canonical bf16 ws buffer. 8 elems/thread.
__global__ __launch_bounds__(256) void xcvt_kernel(const void* __restrict__ x,
    bf16* __restrict__ out, const int* __restrict__ flagp)
{
    const bool f32 = (*flagp) != 0;
    const size_t i = ((size_t)blockIdx.x * 256 + threadIdx.x) * 8;
    U8 d = ld8bf(x, i, f32);
    *reinterpret_cast<uint4*>(out + i) = *reinterpret_cast<const uint4*>(d.v);
}

// WT[n][k] = W[k][n], output bf16. grid (N/32, K/32), block (32,8). (fallback path)
__global__ __launch_bounds__(256) void transpose_kernel(const void* __restrict__ W,
    bf16* __restrict__ WT, int K, int N, const int* __restrict__ flagp)
{
    const bool f32 = (*flagp) != 0;
    __shared__ float tile[32][33];
    const int tx = threadIdx.x, ty = threadIdx.y;
    const int n0 = blockIdx.x * 32, k0 = blockIdx.y * 32;
    #pragma unroll
    for (int r = 0; r < 4; ++r)
        tile[ty + 8*r][tx] = ld1(W, (size_t)(k0 + ty + 8*r) * N + n0 + tx, f32);
    __syncthreads();
    #pragma unroll
    for (int r = 0; r < 4; ++r)
        WT[(size_t)(n0 + ty + 8*r) * K + k0 + tx] = __float2bfloat16(tile[tx][ty + 8*r]);
}

// Fused transpose of ALL weights into contiguous dst: [0,4M) wq..wo (1M each),
// [4M,8M) w1 (N=4096,K=1024), [8M,12M) w2 (N=1024,K=4096). 12288 blocks (32,8).
__global__ __launch_bounds__(256) void wtransall_kernel(const void* __restrict__ wq,
    const void* __restrict__ wk, const void* __restrict__ wv, const void* __restrict__ wo,
    const void* __restrict__ w1, const void* __restrict__ w2,
    bf16* __restrict__ dst, const int* __restrict__ flagp)
{
    const bool f32 = (*flagp) != 0;
    const int id = blockIdx.x;
    const void* W; bf16* WT; int K, N, n0, k0;
    if (id < 4096) {
        const int which = id >> 10, tid = id & 1023;
        W = (which == 0) ? wq : (which == 1) ? wk : (which == 2) ? wv : wo;
        WT = dst + (size_t)which * 1048576; K = 1024; N = 1024;
        n0 = (tid & 31) * 32; k0 = (tid >> 5) * 32;
    } else if (id < 8192) {
        const int tid = id - 4096;
        W = w1; WT = dst + 4194304; K = 1024; N = 4096;
        n0 = (tid & 127) * 32; k0 = (tid >> 7) * 32;
    } else {
        const int tid = id - 8192;
        W = w2; WT = dst + 8388608; K = 4096; N = 1024;
        n0 = (tid & 31) * 32; k0 = (tid >> 5) * 32;
    }
    __shared__ float tile[32][33];
    const int tx = threadIdx.x, ty = threadIdx.y;
    #pragma unroll
    for (int r = 0; r < 4; ++r)
        tile[ty + 8*r][tx] = ld1(W, (size_t)(k0 + ty + 8*r) * N + n0 + tx, f32);
    __syncthreads();
    #pragma unroll
    for (int r = 0; r < 4; ++r)
        WT[(size_t)(n0 + ty + 8*r) * K + k0 + tx] = __float2bfloat16(tile[tx][ty + 8*r]);
}

// VT[(b*16+h)*64 + d][s] = V[(b*SEQ+s)*D_MODEL + h*64 + d]. grid (SEQ/32, 2, 32).
__global__ __launch_bounds__(256) void vtrans_kernel(const bf16* __restrict__ V,
    bf16* __restrict__ VT)
{
    __shared__ unsigned short tile[32][33];
    const int tx = threadIdx.x, ty = threadIdx.y;
    const int s0 = blockIdx.x * 32, d0 = blockIdx.y * 32;
    const int bh = blockIdx.z, b = bh >> 4, h = bh & 15;
    #pragma unroll
    for (int r = 0; r < 4; ++r)
        tile[ty + 8*r][tx] = *reinterpret_cast<const unsigned short*>(
            V + ((size_t)(b * SEQ + s0 + ty + 8*r)) * D_MODEL + h * DK + d0 + tx);
    __syncthreads();
    #pragma unroll
    for (int r = 0; r < 4; ++r)
        *reinterpret_cast<unsigned short*>(
            VT + ((size_t)(bh * DK + d0 + ty + 8*r)) * SEQ + s0 + tx) = tile[tx][ty + 8*r];
}

// MFMA GEMM: C bf16 = A[M,K] @ BT[N,K]^T (+bias)(+relu). 128x128 tile, 4 waves,
// BK=64, global_load_lds staging, XOR-swizzled unpadded LDS.
template<bool RELU, bool BIAS, int NMAT, int SPLITK>
__global__ __launch_bounds__(256) void mgemm_kernel(const bf16* __restrict__ A,
    const bf16* __restrict__ BT, const void* __restrict__ bias,
    bf16* __restrict__ C, int M, int N, int K, const int* __restrict__ flagp)
{
    const bool inF32 = (*flagp) != 0;

    __shared__ unsigned short sA[128 * 64];
    __shared__ unsigned short sB[128 * 64];

    int which = 0, colb = blockIdx.x;
    if (NMAT > 1) { which = blockIdx.x >> 3; colb = blockIdx.x & 7; }
    const int kslice = (SPLITK > 1) ? blockIdx.z : 0;
    const int Kspan  = K / SPLITK;
    const int kbase  = kslice * Kspan;
    const bf16* Bp = BT + (size_t)which * N * K;
    bf16*       Cp = C  + (size_t)which * M * N + (size_t)kslice * M * N;

    const int row0 = blockIdx.y * 128;
    const int col0 = colb * 128;

    const int t    = threadIdx.x;
    const int wave = t >> 6;
    const int lane = t & 63;
    const int lm   = lane & 15;
    const int q    = lane >> 4;
    const int wm   = (wave & 1) * 64;
    const int wn   = (wave >> 1) * 64;

    facc4 acc[4][4];
    #pragma unroll
    for (int i = 0; i < 4; ++i)
        #pragma unroll
        for (int j = 0; j < 4; ++j)
            acc[i][j] = (facc4){0.f, 0.f, 0.f, 0.f};

    for (int k0 = kbase; k0 < kbase + Kspan; k0 += 64) {
        __syncthreads();
        #pragma unroll
        for (int j = 0; j < 4; ++j) {
            const int ch = (wave * 4 + j) * 64 + lane;
            const int r  = ch >> 3;
            const int c  = (ch & 7) ^ (r & 7);
            gld16(A  + (size_t)(row0 + r) * K + k0 + 8 * c, &sA[(wave * 4 + j) * 512]);
            gld16(Bp + (size_t)(col0 + r) * K + k0 + 8 * c, &sB[(wave * 4 + j) * 512]);
        }
        __syncthreads();

        #pragma unroll
        for (int kk = 0; kk < 64; kk += 32) {
            const int cr = (kk >> 3) + q;
            frag8 af[4], bfr[4];
            #pragma unroll
            for (int im = 0; im < 4; ++im) {
                const int m = wm + 16 * im + lm;
                af[im] = *reinterpret_cast<const frag8*>(&sA[m * 64 + ((cr ^ (m & 7)) << 3)]);
            }
            #pragma unroll
            for (int in = 0; in < 4; ++in) {
                const int n = wn + 16 * in + lm;
                bfr[in] = *reinterpret_cast<const frag8*>(&sB[n * 64 + ((cr ^ (n & 7)) << 3)]);
            }
            #pragma unroll
            for (int im = 0; im < 4; ++im)
                #pragma unroll
                for (int in = 0; in < 4; ++in)
                    acc[im][in] = __builtin_amdgcn_mfma_f32_16x16x32_bf16(af[im], bfr[in], acc[im][in], 0, 0, 0);
        }
    }

    #pragma unroll
    for (int in = 0; in < 4; ++in) {
        const int col = col0 + wn + 16*in + lm;
        float bv = 0.f;
        if (BIAS && kslice == 0) bv = ld1(bias, col, inF32);
        #pragma unroll
        for (int im = 0; im < 4; ++im) {
            #pragma unroll
            for (int r = 0; r < 4; ++r) {
                const int row = row0 + wm + 16*im + 4*q + r;
                float v = acc[im][in][r] + bv;
                if (RELU) v = fmaxf(v, 0.f);
                Cp[(size_t)row * N + col] = __float2bfloat16(v);
            }
        }
    }
}

// MFMA flash attention v4: 128 q-rows/block, 512 threads (8 waves x 16 rows).
// K-tile 64 -> LDS ~35 KB -> up to 4 blocks/CU (32 waves/CU). exp2-domain softmax
// (Q pre-scaled by 0.125*log2e). K/VT via global_load_lds, XOR-swizzled.
__global__ __launch_bounds__(512) void fattn_kernel(
    const bf16* __restrict__ Qg, const bf16* __restrict__ Kg,
    const bf16* __restrict__ VTg, const int* __restrict__ mask,
    bf16* __restrict__ ctx)
{
    __shared__ unsigned short sK[64 * 64];        // 8 KB, swizzled [kk][d]
    __shared__ unsigned short sV[64 * 64];        // 8 KB, swizzled [d][kk]
    __shared__ unsigned short PsU[8 * 16 * SSTR]; // 18.4 KB; Qs overlays entirely
    __shared__ float madd[64];

    const int t    = threadIdx.x;
    const int qt   = blockIdx.x;
    const int h    = blockIdx.y;
    const int b    = blockIdx.z;
    const int q0   = qt * 128;
    const int bh   = b * N_HEADS + h;
    const int wave = t >> 6;
    const int lane = t & 63;
    const int lm   = lane & 15;
    const int qd   = lane >> 4;

    // ---- stage Q (scaled 0.125*log2e) into PsU overlay; hoist fragments ----
    unsigned short* Qs = PsU;
    {
        const int sr = t >> 2, sd0 = (t & 3) * 16;   // 128 rows x 64 d
        const unsigned short* src = (const unsigned short*)
            (Qg + ((size_t)(b * SEQ + q0 + sr)) * D_MODEL + h * DK + sd0);
        unsigned short qi[16], qo[16];
        *reinterpret_cast<uint4*>(&qi[0]) = *reinterpret_cast<const uint4*>(src);
        *reinterpret_cast<uint4*>(&qi[8]) = *reinterpret_cast<const uint4*>(src + 8);
        #pragma unroll
        for (int u = 0; u < 16; ++u) qo[u] = f2bu(bf2f(qi[u]) * (0.125f * LOG2E));
        *reinterpret_cast<uint4*>(&Qs[sr * SSTR + sd0])     = *reinterpret_cast<const uint4*>(&qo[0]);
        *reinterpret_cast<uint4*>(&Qs[sr * SSTR + sd0 + 8]) = *reinterpret_cast<const uint4*>(&qo[8]);
    }
    __syncthreads();
    frag8 qf[2];
    #pragma unroll
    for (int s2 = 0; s2 < 2; ++s2)
        qf[s2] = *reinterpret_cast<const frag8*>(&Qs[(16 * wave + lm) * SSTR + 32 * s2 + 8 * qd]);

    facc4 accO[4];
    float m_r[4], l_r[4];
    #pragma unroll
    for (int r = 0; r < 4; ++r) { m_r[r] = -1e30f; l_r[r] = 0.f; }
    #pragma unroll
    for (int in = 0; in < 4; ++in) accO[in] = (facc4){0.f, 0.f, 0.f, 0.f};

    for (int kt = 0; kt < SEQ / 64; ++kt) {
        const int k0 = kt * 64;
        __syncthreads();   // sK/sV consumed; also protects Qs->Ps overlay on kt=0

        // ---- stage K [64kk][64d] and VT [64d][64kk], swizzled; 1 chunk/lane ----
        {
            const int r  = t >> 3;
            const int c  = (t & 7) ^ (r & 7);
            gld16(Kg + ((size_t)(b * SEQ + k0 + r)) * D_MODEL + h * DK + 8 * c,
                  &sK[wave * 512]);
            gld16(VTg + ((size_t)(bh * DK + r)) * SEQ + k0 + 8 * c,
                  &sV[wave * 512]);
        }
        if (t < 64) madd[t] = (mask[b * SEQ + k0 + t] == 0) ? -1e9f : 0.f;
        __syncthreads();

        // ---- S[16q][64kk] = Q @ K^T (log2 domain) ----
        facc4 accS[4];
        #pragma unroll
        for (int i = 0; i < 4; ++i) accS[i] = (facc4){0.f, 0.f, 0.f, 0.f};
        #pragma unroll
        for (int i = 0; i < 4; ++i) {
            #pragma unroll
            for (int s2 = 0; s2 < 2; ++s2) {
                const int cr = 4 * s2 + qd;
                frag8 kf = *reinterpret_cast<const frag8*>(
                    &sK[(16 * i + lm) * 64 + ((cr ^ (lm & 7)) << 3)]);
                accS[i] = __builtin_amdgcn_mfma_f32_16x16x32_bf16(qf[s2], kf, accS[i], 0, 0, 0);
            }
        }

        float madv[4];
        #pragma unroll
        for (int i = 0; i < 4; ++i) madv[i] = madd[16 * i + lm];

        float mx[4];
        #pragma unroll
        for (int r = 0; r < 4; ++r) {
            float m0 = -1e30f;
            #pragma unroll
            for (int i = 0; i < 4; ++i) m0 = fmaxf(m0, accS[i][r] + madv[i]);
            #pragma unroll
            for (int off = 1; off < 16; off <<= 1) m0 = fmaxf(m0, __shfl_xor(m0, off));
            mx[r] = m0;
        }

        float alpha[4], mn[4], psum[4];
        #pragma unroll
        for (int r = 0; r < 4; ++r) {
            mn[r] = fmaxf(m_r[r], mx[r]);
            alpha[r] = __builtin_amdgcn_exp2f(m_r[r] - mn[r]);
            m_r[r] = mn[r];
            psum[r] = 0.f;
        }
        unsigned short* Pw = &PsU[wave * 16 * SSTR];
        #pragma unroll
        for (int i = 0; i < 4; ++i) {
            #pragma unroll
            for (int r = 0; r < 4; ++r) {
                float p = __builtin_amdgcn_exp2f(accS[i][r] + madv[i] - mn[r]);
                psum[r] += p;
                Pw[(qd * 4 + r) * SSTR + 16 * i + lm] = f2bu(p);
            }
        }
        #pragma unroll
        for (int r = 0; r < 4; ++r) {
            float s = psum[r];
            #pragma unroll
            for (int off = 1; off < 16; off <<= 1) s += __shfl_xor(s, off);
            l_r[r] = l_r[r] * alpha[r] + s;
            #pragma unroll
            for (int in = 0; in < 4; ++in) accO[in][r] *= alpha[r];
        }

        // ---- O += P @ V (Ps is wave-private; no barrier needed) ----
        #pragma unroll
        for (int c = 0; c < 2; ++c) {
            frag8 pf = *reinterpret_cast<const frag8*>(&Pw[lm * SSTR + 32 * c + 8 * qd]);
            #pragma unroll
            for (int in = 0; in < 4; ++in) {
                const int cr = 4 * c + qd;
                frag8 vf = *reinterpret_cast<const frag8*>(
                    &sV[(16 * in + lm) * 64 + ((cr ^ (lm & 7)) << 3)]);
                accO[in] = __builtin_amdgcn_mfma_f32_16x16x32_bf16(pf, vf, accO[in], 0, 0, 0);
            }
        }
    }

    float inv[4];
    #pragma unroll
    for (int r = 0; r < 4; ++r) inv[r] = 1.f / l_r[r];
    #pragma unroll
    for (int in = 0; in < 4; ++in)
        #pragma unroll
        for (int r = 0; r < 4; ++r)
            ctx[((size_t)(b * SEQ + q0 + 16 * wave + qd * 4 + r)) * D_MODEL + h * DK + 16 * in + lm]
                = __float2bfloat16(accO[in][r] * inv[r]);
}

// LN v2: 4 elems/thread, vector loads, single-pass sum/sumsq, ddof=1.
template<bool BASE_WS, bool OUT_WS>
__global__ __launch_bounds__(256) void ln_kernel(const void* __restrict__ base,
    const bf16* __restrict__ addv, const bf16* __restrict__ addv2,
    const void* __restrict__ alpha, const void* __restrict__ bias,
    void* __restrict__ outp, const int* __restrict__ flagp)
{
    const bool inF32 = (*flagp) != 0;
    __shared__ float2 red[256];
    const int row = blockIdx.x, tid = threadIdx.x;
    const int i0 = 4 * tid;
    const size_t off = (size_t)row * D_MODEL + i0;

    float v[4];
    if (BASE_WS) ld4f(base, off, false, v);
    else         ld4f(base, off, inF32, v);
    {
        const ushort4 u = *reinterpret_cast<const ushort4*>((const unsigned short*)addv + off);
        v[0] += bf2f(u.x); v[1] += bf2f(u.y); v[2] += bf2f(u.z); v[3] += bf2f(u.w);
    }
    if (addv2) {
        const ushort4 u = *reinterpret_cast<const ushort4*>((const unsigned short*)addv2 + off);
        v[0] += bf2f(u.x); v[1] += bf2f(u.y); v[2] += bf2f(u.z); v[3] += bf2f(u.w);
    }

    float s = v[0] + v[1] + v[2] + v[3];
    float sq = v[0]*v[0] + v[1]*v[1] + v[2]*v[2] + v[3]*v[3];
    red[tid] = make_float2(s, sq); __syncthreads();
    for (int st = 128; st > 0; st >>= 1) {
        if (tid < st) { red[tid].x += red[tid + st].x; red[tid].y += red[tid + st].y; }
        __syncthreads();
    }
    const float S = red[0].x, SQ = red[0].y;
    const float mean = S * (1.f / D_MODEL);
    const float var  = (SQ - S * mean) * (1.f / (D_MODEL - 1));
    const float inv  = 1.f / (sqrtf(var) + LN_EPS);

    float la[4], lb[4];
    ld4f(alpha, i0, inF32, la);
    ld4f(bias,  i0, inF32, lb);
    float y[4];
    #pragma unroll
    for (int j = 0; j < 4; ++j) y[j] = la[j] * (v[j] - mean) * inv + lb[j];

    if (OUT_WS || !inF32) {
        ushort4 o;
        o.x = f2bu(y[0]); o.y = f2bu(y[1]); o.z = f2bu(y[2]); o.w = f2bu(y[3]);
        *reinterpret_cast<ushort4*>((unsigned short*)outp + off) = o;
    } else {
        *reinterpret_cast<float4*>((float*)outp + off) = make_float4(y[0], y[1], y[2], y[3]);
    }
}

extern "C" void kernel_launch(void* const* d_in, const int* in_sizes, int n_in,
                              void* d_out, int out_size, void* d_ws, size_t ws_size,
                              hipStream_t stream)
{
    const void* x    = d_in[0];
    const int*  mask = (const int*)d_in[1];
    const void* wq   = d_in[2];
    const void* wk   = d_in[3];
    const void* wv   = d_in[4];
    const void* wo   = d_in[5];
    const void* wo_b = d_in[6];
    const void* w1   = d_in[7];
    const void* b1   = d_in[8];
    const void* w2   = d_in[9];
    const void* b2   = d_in[10];
    const void* al1  = d_in[11];
    const void* bi1  = d_in[12];
    const void* al2  = d_in[13];
    const void* bi2  = d_in[14];

    const size_t MB = 1024 * 1024;
    char* ws = (char*)d_ws;
    const bool BIG = ws_size >= 64 * MB + 4096;
    if (!BIG && ws_size < 56 * MB + 4096) return;   // loud fail: out stays 0

    dim3 tb(32, 8);

    if (BIG) {
        // 64 MB plan:
        //  [0,8)Qb [8,16)Kb [16,24)Vb [24,32)Xb->VTb
        //  [32,40)WT4(wq..wo) | [40,48)W1T | [48,56)W2T  (contiguous transpose dst)
        //  [56,64)CTXb -> X1b ; ATT0 [0,8) ATT1 [8,16) over dead Qb/Kb
        //  FFb [0,32) after ln1 ; X20 [32,40) X21 [40,48) (WT4/W1T dead)
        bf16* Qb   = (bf16*)(ws + 0 * MB);
        bf16* Kb   = (bf16*)(ws + 8 * MB);
        bf16* Vb   = (bf16*)(ws + 16 * MB);
        bf16* Xb   = (bf16*)(ws + 24 * MB);
        bf16* VTb  = (bf16*)(ws + 24 * MB);
        bf16* WT4  = (bf16*)(ws + 32 * MB);
        bf16* WOT  = WT4 + (size_t)3 * D_MODEL * D_MODEL;
        bf16* W1T  = (bf16*)(ws + 40 * MB);
        bf16* W2T  = (bf16*)(ws + 48 * MB);
        bf16* CTXb = (bf16*)(ws + 56 * MB);
        bf16* ATT0 = (bf16*)(ws + 0 * MB);
        bf16* ATT1 = (bf16*)(ws + 8 * MB);
        bf16* X1b  = (bf16*)(ws + 56 * MB);
        bf16* FFb  = (bf16*)(ws + 0 * MB);
        bf16* X20  = (bf16*)(ws + 32 * MB);
        bf16* X21  = (bf16*)(ws + 40 * MB);
        int*  flagp = (int*)(ws + 64 * MB);

        probe_kernel<<<1, 256, 0, stream>>>(x, flagp);
        xcvt_kernel<<<dim3(ROWS * D_MODEL / 2048), 256, 0, stream>>>(x, Xb, flagp);

        wtransall_kernel<<<dim3(12288), tb, 0, stream>>>(wq, wk, wv, wo, w1, w2, WT4, flagp);

        mgemm_kernel<false, false, 3, 1><<<dim3(24, 32), 256, 0, stream>>>(
            Xb, WT4, nullptr, Qb, ROWS, D_MODEL, D_MODEL, flagp);

        vtrans_kernel<<<dim3(SEQ / 32, 2, BATCH * N_HEADS), tb, 0, stream>>>(Vb, VTb);

        fattn_kernel<<<dim3(SEQ / 128, N_HEADS, BATCH), 512, 0, stream>>>(Qb, Kb, VTb, mask, CTXb);

        mgemm_kernel<false, true, 1, 2><<<dim3(8, 32, 2), 256, 0, stream>>>(
            CTXb, WOT, wo_b, ATT0, ROWS, D_MODEL, D_MODEL, flagp);
        ln_kernel<false, true><<<ROWS, 256, 0, stream>>>(x, ATT0, ATT1, al1, bi1, X1b, flagp);

        mgemm_kernel<true, true, 1, 1><<<dim3(32, 32), 256, 0, stream>>>(
            X1b, W1T, b1, FFb, ROWS, D_FF, D_MODEL, flagp);

        mgemm_kernel<false, true, 1, 2><<<dim3(8, 32, 2), 256, 0, stream>>>(
            FFb, W2T, b2, X20, ROWS, D_MODEL, D_FF, flagp);
        ln_kernel<true, false><<<ROWS, 256, 0, stream>>>(X1b, X20, X21, al2, bi2, d_out, flagp);
    } else {
        // 56 MB fallback (R8 layout, no split-K).
        bf16* Qb    = (bf16*)(ws + 0 * MB);
        bf16* Kb    = (bf16*)(ws + 8 * MB);
        bf16* Vb    = (bf16*)(ws + 16 * MB);
        bf16* Xb    = (bf16*)(ws + 24 * MB);
        bf16* VTb   = (bf16*)(ws + 24 * MB);
        bf16* WQKVT = (bf16*)(ws + 32 * MB);
        bf16* CTXb  = (bf16*)(ws + 32 * MB);
        bf16* W2T   = (bf16*)(ws + 32 * MB);
        bf16* WOT   = (bf16*)(ws + 0 * MB);
        bf16* ATT0  = (bf16*)(ws + 48 * MB);
        bf16* W1T   = (bf16*)(ws + 48 * MB);
        bf16* X20   = (bf16*)(ws + 48 * MB);
        bf16* X1b   = (bf16*)(ws + 40 * MB);
        bf16* FFb   = (bf16*)(ws + 0 * MB);
        int*  flagp = (int*)(ws + 56 * MB);

        probe_kernel<<<1, 256, 0, stream>>>(x, flagp);
        xcvt_kernel<<<dim3(ROWS * D_MODEL / 2048), 256, 0, stream>>>(x, Xb, flagp);

        transpose_kernel<<<dim3(32, 32), tb, 0, stream>>>(wq, WQKVT,           D_MODEL, D_MODEL, flagp);
        transpose_kernel<<<dim3(32, 32), tb, 0, stream>>>(wk, WQKVT + 1048576, D_MODEL, D_MODEL, flagp);
        transpose_kernel<<<dim3(32, 32), tb, 0, stream>>>(wv, WQKVT + 2097152, D_MODEL, D_MODEL, flagp);

        mgemm_kernel<false, false, 3, 1><<<dim3(24, 32), 256, 0, stream>>>(
            Xb, WQKVT, nullptr, Qb, ROWS, D_MODEL, D_MODEL, flagp);

        vtrans_kernel<<<dim3(SEQ / 32, 2, BATCH * N_HEADS), tb, 0, stream>>>(Vb, VTb);

        fattn_kernel<<<dim3(SEQ / 128, N_HEADS, BATCH), 512, 0, stream>>>(Qb, Kb, VTb, mask, CTXb);

        transpose_kernel<<<dim3(32, 32), tb, 0, stream>>>(wo, WOT, D_MODEL, D_MODEL, flagp);
        mgemm_kernel<false, true, 1, 1><<<dim3(8, 32), 256, 0, stream>>>(
            CTXb, WOT, wo_b, ATT0, ROWS, D_MODEL, D_MODEL, flagp);
        ln_kernel<false, true><<<ROWS, 256, 0, stream>>>(x, ATT0, nullptr, al1, bi1, X1b, flagp);

        transpose_kernel<<<dim3(128, 32), tb, 0, stream>>>(w1, W1T, D_MODEL, D_FF, flagp);
        mgemm_kernel<true, true, 1, 1><<<dim3(32, 32), 256, 0, stream>>>(
            X1b, W1T, b1, FFb, ROWS, D_FF, D_MODEL, flagp);

        transpose_kernel<<<dim3(32, 128), tb, 0, stream>>>(w2, W2T, D_FF, D_MODEL, flagp);
        mgemm_kernel<false, true, 1, 1><<<dim3(8, 32), 256, 0, stream>>>(
            FFb, W2T, b2, X20, ROWS, D_MODEL, D_FF, flagp);
        ln_kernel<true, false><<<ROWS, 256, 0, stream>>>(X1b, X20, nullptr, al2, bi2, d_out, flagp);
    }
}